// Round 8
// baseline (2457.163 us; speedup 1.0000x reference)
//
#include <hip/hip_runtime.h>

// ECGLSTM: B=256, T=5000, input_size=1, H=64, fused FC(64->128)+ReLU.
// R11: R9/R10 (quad layout + DPP row_ror dot) + IN-LOOP weight pins.
//   - R10's pin was OUTSIDE the t-loop: it forced VGPR-ness at one point,
//     then the allocator parked the weights in AGPRs / rematerialized them
//     anyway (VGPR_Count stayed 48; accvgpr reads are invisible in both
//     WRITE_SIZE and FETCH_SIZE). ~64 extra ops + hazards every step.
//   - Fix: empty `asm volatile("" : "+v"(w))` per weight AT THE TOP OF EVERY
//     ITERATION. Emits zero instructions, but each weight becomes a
//     loop-carried opaque value: not rematerializable (the asm "redefines"
//     it) and AGPR residency would cost a->v + v->a copies per iteration vs
//     free VGPR residency -> allocator must keep all 64 in arch VGPRs.
//   - This is the first variant with BOTH known plateaus fixed at once:
//       * LDS pipe: 4 conflict-free ds_read_b32 bases + register-only DPP
//         rotations (~100cy/step) instead of 64 ds_read_b128/CU (~770cy).
//       * Weights: register-resident (no per-step reloads/accvgpr traffic).
//   - Everything else byte-identical to R10 (passed, absmax 4.88e-4).

#define LSTM_H 64
#define LSTM_T 5000
#define LSTM_B 256

__device__ __forceinline__ float fast_rcp(float v) {
    return __builtin_amdgcn_rcpf(v);
}

// Rotate within each 16-lane row by J (direction resolved at runtime by the
// probe; the weight gather uses the probed direction so pairing is correct).
template<int J>
__device__ __forceinline__ float row_ror(float v) {
    return __builtin_bit_cast(float,
        __builtin_amdgcn_mov_dpp(__builtin_bit_cast(int, v),
                                 0x120 + J, 0xF, 0xF, false));
}

// Broadcast lane (quad_base + K) to all 4 lanes of the quad (proven in R7).
template<int K>
__device__ __forceinline__ float quad_bcast(float v) {
    constexpr int ctrl = K | (K << 2) | (K << 4) | (K << 6);  // quad_perm
    return __builtin_bit_cast(float,
        __builtin_amdgcn_mov_dpp(__builtin_bit_cast(int, v),
                                 ctrl, 0xF, 0xF, false));
}

__global__ __launch_bounds__(256, 1) void ECGLSTM_lstm_pin2(
    const float* __restrict__ x,      // [B, T]
    const float* __restrict__ W_ih,   // [4H, 1]
    const float* __restrict__ W_hh,   // [4H, H]
    const float* __restrict__ b_ih,   // [4H]
    const float* __restrict__ b_hh,   // [4H]
    const float* __restrict__ W_fc,   // [128, H]
    const float* __restrict__ b_fc,   // [128]
    float* __restrict__ out)          // [B, 128]
{
    const int tid  = threadIdx.x;     // 0..255
    const int lane = tid & 63;
    const int w    = tid >> 6;        // wave 0..3
    const int g    = lane & 3;        // gate: 0=i 1=f 2=g 3=o
    const int ul   = lane >> 2;       // unit-local 0..15
    const int u    = w * 16 + ul;     // hidden unit 0..63
    const int b    = blockIdx.x;

    __shared__ float xch[LSTM_T];     // whole x row, staged once (20 KB)
    __shared__ float hbuf[2][LSTM_H]; // double-buffered h

    // Stage x (coalesced, once)
    const float* xb = x + b * LSTM_T;
    for (int i = tid; i < LSTM_T; i += 256) xch[i] = xb[i];

    // Probe the hardware row_ror direction: dst[0] = src[(0+e)&15].
    int dirp = __builtin_amdgcn_mov_dpp(lane, 0x121, 0xF, 0xF, false);
    const int e = (__builtin_amdgcn_readlane(dirp, 0) == 1) ? 1 : -1;

    // Gather W_hh row in ROTATION order (once; L2-resident, ~us).
    // At step time, chunk c / offset j delivers h[ ((lane&48)|((lane+e*j)&15)) ^ 16c ].
    const int row = g * LSTM_H + u;
    float wrot[LSTM_H];
    #pragma unroll
    for (int m = 0; m < LSTM_H; ++m) {
        const int cc = m >> 4, jj = m & 15;
        const int k  = (((lane & 48) | ((lane + e * jj) & 15)) ^ (cc << 4));
        wrot[m] = W_hh[row * LSTM_H + k];
    }

    float wih  = W_ih[row];
    float bias = b_ih[row] + b_hh[row];

    const bool  is_t = (g == 2);                  // tanh gate
    const float aexp = is_t ? -2.0f : -1.0f;      // ex = exp(aexp * gate)
    const float smul = is_t ?  2.0f :  1.0f;      // act = s*rcp(1+ex) + d
    const float dadd = is_t ? -1.0f :  0.0f;

    float c = 0.0f;                   // cell state, replicated across the quad
    if (tid < LSTM_H) hbuf[0][tid] = 0.0f;
    __syncthreads();                  // x staged + h0 visible

    // One chunk of the dot: base bc = h[lane^16c]; 15 DPP rotations cover
    // the rest of the 16-lane row. All indices compile-time -> registers.
    #define RF(cN, j) a##cN = fmaf(row_ror<j>(b##cN), wrot[16 * cN + j], a##cN);
    #define CHUNK(cN)                                                          \
        float a##cN = b##cN * wrot[16 * cN];                                   \
        RF(cN, 1)  RF(cN, 2)  RF(cN, 3)  RF(cN, 4)  RF(cN, 5)                  \
        RF(cN, 6)  RF(cN, 7)  RF(cN, 8)  RF(cN, 9)  RF(cN, 10)                 \
        RF(cN, 11) RF(cN, 12) RF(cN, 13) RF(cN, 14) RF(cN, 15)

    #define LSTM_STEP(t, P)                                                    \
    {                                                                          \
        const float* hb = hbuf[(P)];                                           \
        float b0 = hb[lane];                            /* conflict-free */    \
        float b1 = hb[lane ^ 16];                                              \
        float b2 = hb[lane ^ 32];                                              \
        float b3 = hb[lane ^ 48];                                              \
        const float xv = xch[(t)];                      /* broadcast b32 */    \
        CHUNK(0) CHUNK(1) CHUNK(2) CHUNK(3)                                    \
        float dot = (a0 + a1) + (a2 + a3);                                     \
        float gv  = fmaf(xv, wih, bias) + dot;                                 \
        float ex  = __expf(aexp * gv);                                         \
        float act = fmaf(smul, fast_rcp(1.0f + ex), dadd);                     \
        float i_  = quad_bcast<0>(act);                                        \
        float f_  = quad_bcast<1>(act);                                        \
        float g_  = quad_bcast<2>(act);                                        \
        float o_  = quad_bcast<3>(act);                                        \
        c = fmaf(f_, c, i_ * g_);                                              \
        float e2 = __expf(2.0f * c);                                           \
        float th = 1.0f - 2.0f * fast_rcp(e2 + 1.0f);                          \
        if (g == 0) hbuf[1 - (P)][u] = o_ * th;         /* 1 writer/unit */    \
        __syncthreads();                                /* the ONE barrier */  \
    }

    for (int t = 0; t < LSTM_T; t += 2) {
        // IN-LOOP PIN: zero-instruction opaque redefinition of every weight,
        // every iteration. Forces loop-carried arch-VGPR residency: remat
        // from W_hh is illegal (value's provenance is the asm, not memory),
        // AGPR parking costs 2 copies/iter vs 0 for staying in a VGPR.
        #pragma unroll
        for (int m = 0; m < LSTM_H; ++m) asm volatile("" : "+v"(wrot[m]));
        asm volatile("" : "+v"(wih));
        asm volatile("" : "+v"(bias));

        LSTM_STEP(t, 0);
        LSTM_STEP(t + 1, 1);
    }
    #undef LSTM_STEP
    #undef CHUNK
    #undef RF

    // Final h is in hbuf[0] (T even); last step's barrier made it visible.
    // FC(64->128)+ReLU: threads 0..127 compute one output row each.
    if (tid < 128) {
        float s = b_fc[tid];
        const float4* wf = reinterpret_cast<const float4*>(W_fc + tid * LSTM_H);
        const float4* h4 = reinterpret_cast<const float4*>(hbuf[0]);
        #pragma unroll
        for (int i = 0; i < LSTM_H / 4; ++i) {
            float4 wv = wf[i];
            float4 hv = h4[i];
            s = fmaf(hv.x, wv.x, s);
            s = fmaf(hv.y, wv.y, s);
            s = fmaf(hv.z, wv.z, s);
            s = fmaf(hv.w, wv.w, s);
        }
        out[b * 128 + tid] = fmaxf(s, 0.0f);
    }
}

extern "C" void kernel_launch(void* const* d_in, const int* in_sizes, int n_in,
                              void* d_out, int out_size, void* d_ws, size_t ws_size,
                              hipStream_t stream) {
    const float* x    = (const float*)d_in[0];
    const float* W_ih = (const float*)d_in[1];
    const float* W_hh = (const float*)d_in[2];
    const float* b_ih = (const float*)d_in[3];
    const float* b_hh = (const float*)d_in[4];
    const float* W_fc = (const float*)d_in[5];
    const float* b_fc = (const float*)d_in[6];
    float* out = (float*)d_out;

    ECGLSTM_lstm_pin2<<<LSTM_B, 256, 0, stream>>>(
        x, W_ih, W_hh, b_ih, b_hh, W_fc, b_fc, out);
}

// Round 9
// 2326.262 us; speedup vs baseline: 1.0563x; 1.0563x over previous
//
#include <hip/hip_runtime.h>

// ECGLSTM: B=256, T=5000, input_size=1, H=64, fused FC(64->128)+ReLU.
// R12: 512 threads (8 waves, 2/SIMD), k-split rows, chunk-DPP h broadcast.
//   Session evidence: R5's floor = LDS b128 flood (64 ds_read_b128/CU-step
//   ~ 768cy on the one LDS pipe); R8-R11's floor = 64 weights/thread never
//   arch-VGPR-resident (AGPR parking + a<->v shuttles, VGPR_Count pinned
//   at 48 through launch_bounds(256,1) AND asm pins). Fix BOTH:
//   - lane = kh*32 + ul*4 + g; wave w owns units 8w..8w+7. Each thread:
//     gate row (g*64+u), k-half kh -> 32 weights (~60 VGPR total, fits the
//     measured 48-60 budget -> no AGPR parking).
//   - h broadcast: ONE ds_read_b128/lane (chunk c0=((lane&15)>>1)+8kh,
//     adjacent lane pairs share the address = broadcast) + 7 independent
//     DPP row_ror<2j> rotations; DPP 16-lane rows are kh-pure so the 8
//     rotations cover exactly this thread's 8 chunks. LDS pipe ~200cy/CU.
//   - k-half combine: ds_bpermute(lane^32) + add (no LDS mem round trip).
//   - gate exchange: quad_perm within the (kh,ul) quad (proven R7).
//   - 2 waves/SIMD: latency (LDS ~120cy, exp chains, barrier skew) hidden
//     by the co-resident wave -- first variant with any latency hiding.
//   - ONE barrier/step at step end; double-buffered hbuf; race-free
//     (h writes pre-barrier, next step's reads post-barrier).

#define LSTM_H 64
#define LSTM_T 5000
#define LSTM_B 256

__device__ __forceinline__ float fast_rcp(float v) {
    return __builtin_amdgcn_rcpf(v);
}

// Rotate within each 16-lane row by J lanes (direction probed at runtime).
template<int J>
__device__ __forceinline__ float row_ror(float v) {
    return __builtin_bit_cast(float,
        __builtin_amdgcn_mov_dpp(__builtin_bit_cast(int, v),
                                 0x120 + J, 0xF, 0xF, false));
}

// Broadcast lane (quad_base + K) to all 4 lanes of the quad (proven in R7).
template<int K>
__device__ __forceinline__ float quad_bcast(float v) {
    constexpr int ctrl = K | (K << 2) | (K << 4) | (K << 6);  // quad_perm
    return __builtin_bit_cast(float,
        __builtin_amdgcn_mov_dpp(__builtin_bit_cast(int, v),
                                 ctrl, 0xF, 0xF, false));
}

__global__ __launch_bounds__(512, 2) void ECGLSTM_lstm_ksplit(
    const float* __restrict__ x,      // [B, T]
    const float* __restrict__ W_ih,   // [4H, 1]
    const float* __restrict__ W_hh,   // [4H, H]
    const float* __restrict__ b_ih,   // [4H]
    const float* __restrict__ b_hh,   // [4H]
    const float* __restrict__ W_fc,   // [128, H]
    const float* __restrict__ b_fc,   // [128]
    float* __restrict__ out)          // [B, 128]
{
    const int tid  = threadIdx.x;     // 0..511
    const int lane = tid & 63;
    const int w    = tid >> 6;        // wave 0..7
    const int g    = lane & 3;        // gate: 0=i 1=f 2=g 3=o
    const int ul   = (lane >> 2) & 7; // unit-local 0..7
    const int kh   = lane >> 5;       // k-half 0/1 (16-lane DPP rows kh-pure)
    const int u    = w * 8 + ul;      // hidden unit 0..63
    const int b    = blockIdx.x;

    __shared__ float xch[LSTM_T];     // whole x row, staged once (20 KB)
    __shared__ float hbuf[2][LSTM_H]; // double-buffered h

    // Stage x (coalesced, once)
    const float* xb = x + b * LSTM_T;
    for (int i = tid; i < LSTM_T; i += 512) xch[i] = xb[i];

    // Probe the hardware row_ror direction: dst[p] = src[(p+e)&15].
    int dirp = __builtin_amdgcn_mov_dpp(lane & 15, 0x121, 0xF, 0xF, false);
    const int e = (__builtin_amdgcn_readlane(dirp, 0) == 1) ? 1 : -1;

    // This thread's base chunk within hbuf (float4 index 0..15):
    const int p  = lane & 15;
    const int c0 = (p >> 1) + 8 * kh;

    // Gather the 32 weights of row (g*64+u), k-half kh, in ROTATION order:
    // after row_ror<2j>, this lane holds chunk cj = ((p>>1)+e*j)&7 + 8*kh,
    // so pair wrotc[4j+i] with W[row][4*cj+i].
    const int row = g * LSTM_H + u;
    float wrotc[32];
    #pragma unroll
    for (int j = 0; j < 8; ++j) {
        const int cj = ((((p >> 1) + e * j) & 7) + 8 * kh);
        #pragma unroll
        for (int i = 0; i < 4; ++i)
            wrotc[4 * j + i] = W_hh[row * LSTM_H + 4 * cj + i];
    }

    const float wih  = W_ih[row];
    const float bias = b_ih[row] + b_hh[row];
    const bool  is_t = (g == 2);                  // tanh gate
    const float aexp = is_t ? -2.0f : -1.0f;      // ex = exp(aexp * gate)
    const float smul = is_t ?  2.0f :  1.0f;      // act = s*rcp(1+ex) + d
    const float dadd = is_t ? -1.0f :  0.0f;

    const int bperm_addr = (lane ^ 32) << 2;      // k-half partner

    float c = 0.0f;                   // cell state (replicated x8 per unit)
    if (tid < LSTM_H) hbuf[0][tid] = 0.0f;
    __syncthreads();                  // x staged + h0 visible

    // One rotation term: component i of the base float4, rotated by 2j lanes,
    // times the matching pre-gathered weight. 4 independent acc chains.
    #define ROT4(j)                                                            \
        a0 = fmaf(row_ror<2*(j)>(hv.x), wrotc[4*(j)],     a0);                 \
        a1 = fmaf(row_ror<2*(j)>(hv.y), wrotc[4*(j) + 1], a1);                 \
        a2 = fmaf(row_ror<2*(j)>(hv.z), wrotc[4*(j) + 2], a2);                 \
        a3 = fmaf(row_ror<2*(j)>(hv.w), wrotc[4*(j) + 3], a3);

    #define LSTM_STEP(t, P)                                                    \
    {                                                                          \
        const float4 hv = reinterpret_cast<const float4*>(hbuf[(P)])[c0];      \
        const float xv = xch[(t)];                      /* broadcast b32 */    \
        float a0 = hv.x * wrotc[0];                                            \
        float a1 = hv.y * wrotc[1];                                            \
        float a2 = hv.z * wrotc[2];                                            \
        float a3 = hv.w * wrotc[3];                                            \
        ROT4(1) ROT4(2) ROT4(3) ROT4(4) ROT4(5) ROT4(6) ROT4(7)                \
        float half_dot = (a0 + a1) + (a2 + a3);                                \
        float other = __builtin_bit_cast(float,                                \
            __builtin_amdgcn_ds_bpermute(bperm_addr,                           \
                __builtin_bit_cast(int, half_dot)));                           \
        float gv  = fmaf(xv, wih, bias) + (half_dot + other);                  \
        float ex  = __expf(aexp * gv);                                         \
        float act = fmaf(smul, fast_rcp(1.0f + ex), dadd);                     \
        float i_  = quad_bcast<0>(act);                                        \
        float f_  = quad_bcast<1>(act);                                        \
        float g_  = quad_bcast<2>(act);                                        \
        float o_  = quad_bcast<3>(act);                                        \
        c = fmaf(f_, c, i_ * g_);                                              \
        float e2 = __expf(2.0f * c);                                           \
        float th = 1.0f - 2.0f * fast_rcp(e2 + 1.0f);                          \
        if ((lane & 35) == 0) hbuf[1 - (P)][u] = o_ * th; /* g==0 && kh==0 */  \
        __syncthreads();                                /* the ONE barrier */  \
    }

    for (int t = 0; t < LSTM_T; t += 2) {
        LSTM_STEP(t, 0);
        LSTM_STEP(t + 1, 1);
    }
    #undef LSTM_STEP
    #undef ROT4

    // Final h is in hbuf[0] (T even); last step's barrier made it visible.
    // FC(64->128)+ReLU: threads 0..127 compute one output row each.
    if (tid < 128) {
        float s = b_fc[tid];
        const float4* wf = reinterpret_cast<const float4*>(W_fc + tid * LSTM_H);
        const float4* h4 = reinterpret_cast<const float4*>(hbuf[0]);
        #pragma unroll
        for (int i = 0; i < LSTM_H / 4; ++i) {
            float4 wv = wf[i];
            float4 hv = h4[i];
            s = fmaf(hv.x, wv.x, s);
            s = fmaf(hv.y, wv.y, s);
            s = fmaf(hv.z, wv.z, s);
            s = fmaf(hv.w, wv.w, s);
        }
        out[b * 128 + tid] = fmaxf(s, 0.0f);
    }
}

extern "C" void kernel_launch(void* const* d_in, const int* in_sizes, int n_in,
                              void* d_out, int out_size, void* d_ws, size_t ws_size,
                              hipStream_t stream) {
    const float* x    = (const float*)d_in[0];
    const float* W_ih = (const float*)d_in[1];
    const float* W_hh = (const float*)d_in[2];
    const float* b_ih = (const float*)d_in[3];
    const float* b_hh = (const float*)d_in[4];
    const float* W_fc = (const float*)d_in[5];
    const float* b_fc = (const float*)d_in[6];
    float* out = (float*)d_out;

    ECGLSTM_lstm_ksplit<<<LSTM_B, 512, 0, stream>>>(
        x, W_ih, W_hh, b_ih, b_hh, W_fc, b_fc, out);
}

// Round 10
// 2319.920 us; speedup vs baseline: 1.0592x; 1.0027x over previous
//
#include <hip/hip_runtime.h>

// ECGLSTM: B=256, T=5000, input_size=1, H=64, fused FC(64->128)+ReLU.
// R13: R12 (512 thr, k-split, chunk-DPP dot) + VOLATILE-DEF weight pinning.
//   Root cause finally identified across R5-R12: the weights were NEVER
//   register-resident in ANY variant (VGPR_Count 32-52 throughout). The
//   compiler's remat heuristic re-loads W_hh from cache inside the 5000-
//   step loop -> every CU streams 64 KB/step from L2 (W_hh doesn't fit L1)
//   ~= 1000 cy/step = the 2000-2500 us plateau every structure hit.
//   "+v" pins (R10/R11) failed: satisfiable by remat-right-before-pin.
//   - Fix: each weight = OUTPUT of `asm volatile(v_mov_b32)`. Volatile asm
//     cannot be re-executed/hoisted/CSE'd, and the value cannot be re-
//     derived from memory -> the 32 weights/thread MUST stay live in regs
//     across the whole t-loop. At launch_bounds(512,2) budget=256 VGPR,
//     usage ~80 -> no pressure, no AGPR parking, no scratch.
//   - Everything else byte-identical to R12 (passed, absmax 3.8e-6):
//     lane = kh*32 + ul*4 + g; ONE ds_read_b128 h-base + 7 DPP row_ror
//     rotations; k-half combine via ds_bpermute(lane^32); quad_perm gate
//     exchange; one barrier/step; double-buffered hbuf; x staged to LDS.

#define LSTM_H 64
#define LSTM_T 5000
#define LSTM_B 256

__device__ __forceinline__ float fast_rcp(float v) {
    return __builtin_amdgcn_rcpf(v);
}

// Rotate within each 16-lane row by J lanes (direction probed at runtime).
template<int J>
__device__ __forceinline__ float row_ror(float v) {
    return __builtin_bit_cast(float,
        __builtin_amdgcn_mov_dpp(__builtin_bit_cast(int, v),
                                 0x120 + J, 0xF, 0xF, false));
}

// Broadcast lane (quad_base + K) to all 4 lanes of the quad (proven in R7).
template<int K>
__device__ __forceinline__ float quad_bcast(float v) {
    constexpr int ctrl = K | (K << 2) | (K << 4) | (K << 6);  // quad_perm
    return __builtin_bit_cast(float,
        __builtin_amdgcn_mov_dpp(__builtin_bit_cast(int, v),
                                 ctrl, 0xF, 0xF, false));
}

__global__ __launch_bounds__(512, 2) void ECGLSTM_lstm_pinv(
    const float* __restrict__ x,      // [B, T]
    const float* __restrict__ W_ih,   // [4H, 1]
    const float* __restrict__ W_hh,   // [4H, H]
    const float* __restrict__ b_ih,   // [4H]
    const float* __restrict__ b_hh,   // [4H]
    const float* __restrict__ W_fc,   // [128, H]
    const float* __restrict__ b_fc,   // [128]
    float* __restrict__ out)          // [B, 128]
{
    const int tid  = threadIdx.x;     // 0..511
    const int lane = tid & 63;
    const int w    = tid >> 6;        // wave 0..7
    const int g    = lane & 3;        // gate: 0=i 1=f 2=g 3=o
    const int ul   = (lane >> 2) & 7; // unit-local 0..7
    const int kh   = lane >> 5;       // k-half 0/1 (16-lane DPP rows kh-pure)
    const int u    = w * 8 + ul;      // hidden unit 0..63
    const int b    = blockIdx.x;

    __shared__ float xch[LSTM_T];     // whole x row, staged once (20 KB)
    __shared__ float hbuf[2][LSTM_H]; // double-buffered h

    // Stage x (coalesced, once)
    const float* xb = x + b * LSTM_T;
    for (int i = tid; i < LSTM_T; i += 512) xch[i] = xb[i];

    // Probe the hardware row_ror direction: dst[p] = src[(p+e)&15].
    int dirp = __builtin_amdgcn_mov_dpp(lane & 15, 0x121, 0xF, 0xF, false);
    const int e = (__builtin_amdgcn_readlane(dirp, 0) == 1) ? 1 : -1;

    // This thread's base chunk within hbuf (float4 index 0..15):
    const int p  = lane & 15;
    const int c0 = (p >> 1) + 8 * kh;

    // Gather the 32 weights of row (g*64+u), k-half kh, in ROTATION order:
    // after row_ror<2j>, this lane holds chunk cj = ((p>>1)+e*j)&7 + 8*kh,
    // so pair wrotc[4j+i] with W[row][4*cj+i].
    const int row = g * LSTM_H + u;
    float wrotc[32];
    #pragma unroll
    for (int j = 0; j < 8; ++j) {
        const int cj = ((((p >> 1) + e * j) & 7) + 8 * kh);
        #pragma unroll
        for (int i = 0; i < 4; ++i)
            wrotc[4 * j + i] = W_hh[row * LSTM_H + 4 * cj + i];
    }

    float wih  = W_ih[row];
    float bias = b_ih[row] + b_hh[row];

    // PIN (the R13 fix): redefine every loop-invariant weight as the output
    // of a volatile v_mov_b32. Volatile asm can't be re-executed, hoisted,
    // or CSE'd, and its output can't be rematerialized from W_hh -> the 32
    // weights + wih + bias MUST occupy live VGPRs across the whole t-loop.
    // Kills the per-step 64KB/CU L2 weight stream that floored R5-R12.
    #pragma unroll
    for (int m = 0; m < 32; ++m) {
        float tmp = wrotc[m];
        asm volatile("v_mov_b32 %0, %1" : "=v"(wrotc[m]) : "v"(tmp));
    }
    {
        float tmp = wih;
        asm volatile("v_mov_b32 %0, %1" : "=v"(wih) : "v"(tmp));
        tmp = bias;
        asm volatile("v_mov_b32 %0, %1" : "=v"(bias) : "v"(tmp));
    }

    const bool  is_t = (g == 2);                  // tanh gate
    const float aexp = is_t ? -2.0f : -1.0f;      // ex = exp(aexp * gate)
    const float smul = is_t ?  2.0f :  1.0f;      // act = s*rcp(1+ex) + d
    const float dadd = is_t ? -1.0f :  0.0f;

    const int bperm_addr = (lane ^ 32) << 2;      // k-half partner

    float c = 0.0f;                   // cell state (replicated x8 per unit)
    if (tid < LSTM_H) hbuf[0][tid] = 0.0f;
    __syncthreads();                  // x staged + h0 visible

    // One rotation term: component i of the base float4, rotated by 2j lanes,
    // times the matching pre-gathered weight. 4 independent acc chains.
    #define ROT4(j)                                                            \
        a0 = fmaf(row_ror<2*(j)>(hv.x), wrotc[4*(j)],     a0);                 \
        a1 = fmaf(row_ror<2*(j)>(hv.y), wrotc[4*(j) + 1], a1);                 \
        a2 = fmaf(row_ror<2*(j)>(hv.z), wrotc[4*(j) + 2], a2);                 \
        a3 = fmaf(row_ror<2*(j)>(hv.w), wrotc[4*(j) + 3], a3);

    #define LSTM_STEP(t, P)                                                    \
    {                                                                          \
        const float4 hv = reinterpret_cast<const float4*>(hbuf[(P)])[c0];      \
        const float xv = xch[(t)];                      /* broadcast b32 */    \
        float a0 = hv.x * wrotc[0];                                            \
        float a1 = hv.y * wrotc[1];                                            \
        float a2 = hv.z * wrotc[2];                                            \
        float a3 = hv.w * wrotc[3];                                            \
        ROT4(1) ROT4(2) ROT4(3) ROT4(4) ROT4(5) ROT4(6) ROT4(7)                \
        float half_dot = (a0 + a1) + (a2 + a3);                                \
        float other = __builtin_bit_cast(float,                                \
            __builtin_amdgcn_ds_bpermute(bperm_addr,                           \
                __builtin_bit_cast(int, half_dot)));                           \
        float gv  = fmaf(xv, wih, bias) + (half_dot + other);                  \
        float ex  = __expf(aexp * gv);                                         \
        float act = fmaf(smul, fast_rcp(1.0f + ex), dadd);                     \
        float i_  = quad_bcast<0>(act);                                        \
        float f_  = quad_bcast<1>(act);                                        \
        float g_  = quad_bcast<2>(act);                                        \
        float o_  = quad_bcast<3>(act);                                        \
        c = fmaf(f_, c, i_ * g_);                                              \
        float e2 = __expf(2.0f * c);                                           \
        float th = 1.0f - 2.0f * fast_rcp(e2 + 1.0f);                          \
        if ((lane & 35) == 0) hbuf[1 - (P)][u] = o_ * th; /* g==0 && kh==0 */  \
        __syncthreads();                                /* the ONE barrier */  \
    }

    for (int t = 0; t < LSTM_T; t += 2) {
        LSTM_STEP(t, 0);
        LSTM_STEP(t + 1, 1);
    }
    #undef LSTM_STEP
    #undef ROT4

    // Final h is in hbuf[0] (T even); last step's barrier made it visible.
    // FC(64->128)+ReLU: threads 0..127 compute one output row each.
    if (tid < 128) {
        float s = b_fc[tid];
        const float4* wf = reinterpret_cast<const float4*>(W_fc + tid * LSTM_H);
        const float4* h4 = reinterpret_cast<const float4*>(hbuf[0]);
        #pragma unroll
        for (int i = 0; i < LSTM_H / 4; ++i) {
            float4 wv = wf[i];
            float4 hv = h4[i];
            s = fmaf(hv.x, wv.x, s);
            s = fmaf(hv.y, wv.y, s);
            s = fmaf(hv.z, wv.z, s);
            s = fmaf(hv.w, wv.w, s);
        }
        out[b * 128 + tid] = fmaxf(s, 0.0f);
    }
}

extern "C" void kernel_launch(void* const* d_in, const int* in_sizes, int n_in,
                              void* d_out, int out_size, void* d_ws, size_t ws_size,
                              hipStream_t stream) {
    const float* x    = (const float*)d_in[0];
    const float* W_ih = (const float*)d_in[1];
    const float* W_hh = (const float*)d_in[2];
    const float* b_ih = (const float*)d_in[3];
    const float* b_hh = (const float*)d_in[4];
    const float* W_fc = (const float*)d_in[5];
    const float* b_fc = (const float*)d_in[6];
    float* out = (float*)d_out;

    ECGLSTM_lstm_pinv<<<LSTM_B, 512, 0, stream>>>(
        x, W_ih, W_hh, b_ih, b_hh, W_fc, b_fc, out);
}

// Round 13
// 2195.985 us; speedup vs baseline: 1.1189x; 1.0564x over previous
//
#include <hip/hip_runtime.h>

// ECGLSTM: B=256, T=5000, input_size=1, H=64, fused FC(64->128)+ReLU.
// R15: 2-wave blocks, 2 gate rows/lane, weights in 128 VGPRs.
//   Session facts: (a) the ONLY config that ever allocated big was R6's
//   64-thread block (VGPR_Count=256, spilled rather than remat) -- block
//   shape drives the allocator's occupancy heuristic; 256/512-thread
//   blocks pinned at 32-52 VGPRs through every pin attempt. (b) R14
//   proved MFMA needs a 6-group precision scheme = 933cy/step (no win).
//   So: smallest block that closes the gate exchange = 128 thr / 2 waves,
//   2 gate rows per lane = 128 weight VGPRs (~185 total < 256 arch cap).
//   - lane = hidden unit. wave0: gates i,f; wave1: g,o.
//   - h in REGISTERS. Broadcast in-wave: bases h[lane^16] via
//     ds_swizzle(0x401F), h[lane^32]/h[lane^48] via ds_bpermute (both
//     HW-verified this session), + DPP row_ror<j> rotations (R9-verified
//     formula + runtime direction probe). Rotations SHARED by both rows.
//   - Dot: 64 rot/swz + 64 v_pk_fma (R5-proven asm) ~ 256cy issue.
//   - Gate exchange: 2 ds_write + ONE barrier + 2 ds_read (parity dbuf);
//     c,h updated replicated in both waves (bitwise-identical f32).
//   - amdgpu_waves_per_eu(1,1): occupancy is explicitly not a goal.
//   - All f32 (no bf16 anywhere): absmax expected ~5e-4 (R9 class).

#define LSTM_H 64
#define LSTM_T 5000
#define LSTM_B 256

typedef float v2f __attribute__((ext_vector_type(2)));

__device__ __forceinline__ void pk_fma_acc(v2f& acc, v2f a, v2f b) {
    asm("v_pk_fma_f32 %0, %1, %2, %0" : "+v"(acc) : "v"(a), "v"(b));
}
__device__ __forceinline__ float fast_rcp(float v) {
    return __builtin_amdgcn_rcpf(v);
}
// Rotate within each 16-lane row by J (direction probed at runtime).
template<int J>
__device__ __forceinline__ float row_ror(float v) {
    if constexpr (J == 0) return v;
    else return __builtin_bit_cast(float,
        __builtin_amdgcn_mov_dpp(__builtin_bit_cast(int, v),
                                 0x120 + J, 0xF, 0xF, false));
}
__device__ __forceinline__ float swz16(float v) {   // lane ^ 16 (BitMode xor)
    return __builtin_bit_cast(float,
        __builtin_amdgcn_ds_swizzle(__builtin_bit_cast(int, v), 0x401F));
}
__device__ __forceinline__ float bperm(int addr, float v) {
    return __builtin_bit_cast(float,
        __builtin_amdgcn_ds_bpermute(addr, __builtin_bit_cast(int, v)));
}

__global__ __attribute__((amdgpu_flat_work_group_size(128, 128),
                          amdgpu_waves_per_eu(1, 1)))
void ECGLSTM_lstm_2w(
    const float* __restrict__ x,      // [B, T]
    const float* __restrict__ W_ih,   // [4H, 1]
    const float* __restrict__ W_hh,   // [4H, H]
    const float* __restrict__ b_ih,   // [4H]
    const float* __restrict__ b_hh,   // [4H]
    const float* __restrict__ W_fc,   // [128, H]
    const float* __restrict__ b_fc,   // [128]
    float* __restrict__ out)          // [B, 128]
{
    const int tid  = threadIdx.x;     // 0..127
    const int lane = tid & 63;        // hidden unit
    const bool w1  = (tid >> 6) != 0; // wave1?
    const int b    = blockIdx.x;

    __shared__ float xch[LSTM_T];          // x row, staged once (20 KB)
    __shared__ float ex[2][4][LSTM_H];     // parity-dbuf gate exchange (2 KB)
    __shared__ float hfin[LSTM_H];

    const float* xb = x + b * LSTM_T;
    for (int i = tid; i < LSTM_T; i += 128) xch[i] = xb[i];

    // Probe hardware row_ror direction (R9-verified): dst[0]=src[(0+e)&15].
    int dirp = __builtin_amdgcn_mov_dpp(lane & 15, 0x121, 0xF, 0xF, false);
    const int e = (__builtin_amdgcn_readlane(dirp, 0) == 1) ? 1 : -1;

    // Two gate rows per lane, weights in ROTATION order (R9 formula):
    // k(m) = ((lane&48)^((m>>4)<<4)) | ((lane + e*(m&15)) & 15)
    const int GA = w1 ? 2 : 0;        // wave0: i ; wave1: g
    const int GB = w1 ? 3 : 1;        // wave0: f ; wave1: o
    const int rowA = GA * LSTM_H + lane;
    const int rowB = GB * LSTM_H + lane;
    v2f wa2[32], wb2[32];
    #pragma unroll
    for (int m2 = 0; m2 < 32; ++m2) {
        const int m0 = 2 * m2, m1 = 2 * m2 + 1;
        const int k0 = ((lane & 48) ^ ((m0 >> 4) << 4)) | ((lane + e * (m0 & 15)) & 15);
        const int k1 = ((lane & 48) ^ ((m1 >> 4) << 4)) | ((lane + e * (m1 & 15)) & 15);
        wa2[m2] = v2f{W_hh[rowA * LSTM_H + k0], W_hh[rowA * LSTM_H + k1]};
        wb2[m2] = v2f{W_hh[rowB * LSTM_H + k0], W_hh[rowB * LSTM_H + k1]};
    }
    const float wihA  = W_ih[rowA],  wihB  = W_ih[rowB];
    const float biasA = b_ih[rowA] + b_hh[rowA];
    const float biasB = b_ih[rowB] + b_hh[rowB];
    // slot A activation: wave0 -> i (sigmoid); wave1 -> g (tanh). B: sigmoid.
    const float aexpA = w1 ? -2.0f : -1.0f;
    const float smulA = w1 ?  2.0f :  1.0f;
    const float daddA = w1 ? -1.0f :  0.0f;
    const int wsl = w1 ? 2 : 0;       // my write slots: wsl, wsl+1
    const int osl = w1 ? 0 : 2;       // other wave's slots
    const int a32 = (lane ^ 32) << 2, a48 = (lane ^ 48) << 2;

    float h = 0.0f, c = 0.0f;
    float b0 = 0.0f, b1 = 0.0f, b2 = 0.0f, b3 = 0.0f;   // h[lane^{0,16,32,48}]
    __syncthreads();                  // x staged

    #define DOT_CJ(cc, j2, bb)                                                 \
    {                                                                          \
        float h0 = row_ror<2*(j2)>(bb);                                        \
        float h1 = row_ror<2*(j2)+1>(bb);                                      \
        v2f h2{h0, h1};                                                        \
        pk_fma_acc(aA[(cc)&1], h2, wa2[8*(cc)+(j2)]);                          \
        pk_fma_acc(aB[(cc)&1], h2, wb2[8*(cc)+(j2)]);                          \
    }
    #define DOT_CHUNK(cc, bb) \
        DOT_CJ(cc,0,bb) DOT_CJ(cc,1,bb) DOT_CJ(cc,2,bb) DOT_CJ(cc,3,bb) \
        DOT_CJ(cc,4,bb) DOT_CJ(cc,5,bb) DOT_CJ(cc,6,bb) DOT_CJ(cc,7,bb)

    #define LSTM_STEP(t, P)                                                    \
    {                                                                          \
        const float xv = xch[(t)];                                             \
        v2f aA[2] = {v2f{0.f,0.f}, v2f{0.f,0.f}};                              \
        v2f aB[2] = {v2f{0.f,0.f}, v2f{0.f,0.f}};                              \
        DOT_CHUNK(0, b0) DOT_CHUNK(1, b1) DOT_CHUNK(2, b2) DOT_CHUNK(3, b3)    \
        float dA = (aA[0].x + aA[0].y) + (aA[1].x + aA[1].y);                  \
        float dB = (aB[0].x + aB[0].y) + (aB[1].x + aB[1].y);                  \
        float gA = fmaf(xv, wihA, biasA) + dA;                                 \
        float gB = fmaf(xv, wihB, biasB) + dB;                                 \
        float eA = __expf(aexpA * gA);                                         \
        float actA = fmaf(smulA, fast_rcp(1.0f + eA), daddA);                  \
        float eB = __expf(-gB);                                                \
        float actB = fast_rcp(1.0f + eB);                                      \
        ex[(P)][wsl][lane]     = actA;                                         \
        ex[(P)][wsl + 1][lane] = actB;                                         \
        __syncthreads();                                /* the ONE barrier */  \
        float o0 = ex[(P)][osl][lane];                                         \
        float o1 = ex[(P)][osl + 1][lane];                                     \
        float ig = w1 ? o0 : actA;                                             \
        float fg = w1 ? o1 : actB;                                             \
        float gg = w1 ? actA : o0;                                             \
        float og = w1 ? actB : o1;                                             \
        c = fmaf(fg, c, ig * gg);                                              \
        float e2 = __expf(2.0f * c);                                           \
        float th = 1.0f - 2.0f * fast_rcp(e2 + 1.0f);                          \
        h = og * th;                                                           \
        b0 = h;                                                                \
        b1 = swz16(h);                                                         \
        b2 = bperm(a32, h);                                                    \
        b3 = bperm(a48, h);                                                    \
    }

    for (int t = 0; t < LSTM_T; t += 2) {
        LSTM_STEP(t, 0);
        LSTM_STEP(t + 1, 1);
    }
    #undef LSTM_STEP
    #undef DOT_CHUNK
    #undef DOT_CJ

    // FC(64->128)+ReLU. Both waves hold identical h; wave0 publishes it.
    if (tid < LSTM_H) hfin[tid] = h;
    __syncthreads();
    {
        float s = b_fc[tid];
        const float4* wf = reinterpret_cast<const float4*>(W_fc + tid * LSTM_H);
        const float4* h4 = reinterpret_cast<const float4*>(hfin);
        #pragma unroll
        for (int i = 0; i < LSTM_H / 4; ++i) {
            float4 wv = wf[i];
            float4 hv = h4[i];
            s = fmaf(hv.x, wv.x, s);
            s = fmaf(hv.y, wv.y, s);
            s = fmaf(hv.z, wv.z, s);
            s = fmaf(hv.w, wv.w, s);
        }
        out[b * 128 + tid] = fmaxf(s, 0.0f);
    }
}

extern "C" void kernel_launch(void* const* d_in, const int* in_sizes, int n_in,
                              void* d_out, int out_size, void* d_ws, size_t ws_size,
                              hipStream_t stream) {
    const float* x    = (const float*)d_in[0];
    const float* W_ih = (const float*)d_in[1];
    const float* W_hh = (const float*)d_in[2];
    const float* b_ih = (const float*)d_in[3];
    const float* b_hh = (const float*)d_in[4];
    const float* W_fc = (const float*)d_in[5];
    const float* b_fc = (const float*)d_in[6];
    float* out = (float*)d_out;

    hipLaunchKernelGGL(ECGLSTM_lstm_2w, dim3(LSTM_B), dim3(128), 0, stream,
                       x, W_ih, W_hh, b_ih, b_hh, W_fc, b_fc, out);
}